// Round 7
// baseline (692.087 us; speedup 1.0000x reference)
//
#include <hip/hip_runtime.h>

#define H 128
typedef unsigned short ushort_t;
typedef unsigned int uint_t;
using s16x8 = __attribute__((ext_vector_type(8))) short;
using f32x4 = __attribute__((ext_vector_type(4))) float;

// ---------------------------------------------------------------- bf16 helpers
__device__ __forceinline__ ushort_t f2bf(float x) {  // RNE
  uint_t u = __float_as_uint(x);
  return (ushort_t)((u + 0x7fff + ((u >> 16) & 1)) >> 16);
}
__device__ __forceinline__ float bflo(uint_t u) { return __uint_as_float(u << 16); }
__device__ __forceinline__ float bfhi(uint_t u) { return __uint_as_float(u & 0xffff0000u); }

// ---------------------------------------------------------------- async global->LDS 16B
__device__ __forceinline__ void gload_lds16(const void* g, void* l) {
  __builtin_amdgcn_global_load_lds(
      (const __attribute__((address_space(1))) unsigned int*)(unsigned long long)g,
      (__attribute__((address_space(3))) unsigned int*)(unsigned int)(unsigned long long)l,
      16, 0, 0);
}

// ---------------------------------------------------------------- zero ints
__global__ void zero_i32(int* __restrict__ p, int n) {
  int i = blockIdx.x * blockDim.x + threadIdx.x;
  int s = gridDim.x * blockDim.x;
  for (; i < n; i += s) p[i] = 0;
}

// ---------------------------------------------------------------- fp32 -> bf16 (two srcs, contiguous dst)
__global__ void cvt2_bf16(const float* __restrict__ a, const float* __restrict__ b,
                          size_t n4a, size_t n4tot, uint2* __restrict__ out) {
  size_t i = (size_t)blockIdx.x * blockDim.x + threadIdx.x;
  size_t s = (size_t)gridDim.x * blockDim.x;
  for (; i < n4tot; i += s) {
    float4 v = (i < n4a) ? ((const float4*)a)[i] : ((const float4*)b)[i - n4a];
    uint2 r;
    r.x = (uint_t)f2bf(v.x) | ((uint_t)f2bf(v.y) << 16);
    r.y = (uint_t)f2bf(v.z) | ((uint_t)f2bf(v.w) << 16);
    out[i] = r;
  }
}

// ------------------------------------------- 4 W-pairs -> MFMA B-fragment layout
__global__ void build_wfrag4(const float* __restrict__ Wl0, const float* __restrict__ Wr0,
                             const float* __restrict__ Wl1, const float* __restrict__ Wr1,
                             const float* __restrict__ Wl2, const float* __restrict__ Wr2,
                             const float* __restrict__ Wl3, const float* __restrict__ Wr3,
                             ushort_t* __restrict__ dst) {
  int i = blockIdx.x * 256 + threadIdx.x;  // 0..131071
  int w = i >> 15;
  int ii = i & 32767;
  int j = ii & 7;
  int lane = (ii >> 3) & 63;
  int nf = (ii >> 9) & 7;
  int ks = ii >> 12;
  int k = ks * 32 + (lane >> 4) * 8 + j;
  int nn = nf * 16 + (lane & 15);
  const float* Wl = (w == 0) ? Wl0 : (w == 1) ? Wl1 : (w == 2) ? Wl2 : Wl3;
  const float* Wr = (w == 0) ? Wr0 : (w == 1) ? Wr1 : (w == 2) ? Wr2 : Wr3;
  float v = (k < H) ? Wl[k * H + nn] : Wr[(k - H) * H + nn];
  dst[i] = f2bf(v);
}

// ---------------------------------------------------------------- merged histogram (edges + labels)
__global__ void hist_all(const int* __restrict__ src, const int* __restrict__ dst,
                         const int* __restrict__ ld,
                         int* __restrict__ cnt_t, int* __restrict__ cnt_e,
                         int* __restrict__ cnt_l, int E, int L) {
  int i = blockIdx.x * blockDim.x + threadIdx.x;
  int s = gridDim.x * blockDim.x;
  int M = E > L ? E : L;
  for (; i < M; i += s) {
    if (i < E) {
      atomicAdd(&cnt_t[dst[i]], 1);
      atomicAdd(&cnt_e[src[i]], 1);
    }
    if (i < L) atomicAdd(&cnt_l[ld[i]], 1);
  }
}

// ---------------------------------------------------------------- 3-phase exclusive scan
__global__ void scan1(const int* __restrict__ in, int* __restrict__ out,
                      int* __restrict__ part, int n) {
  __shared__ int s[256];
  int t = threadIdx.x;
  int i = blockIdx.x * 256 + t;
  int v = (i < n) ? in[i] : 0;
  s[t] = v;
  __syncthreads();
  for (int off = 1; off < 256; off <<= 1) {
    int tmp = (t >= off) ? s[t - off] : 0;
    __syncthreads();
    s[t] += tmp;
    __syncthreads();
  }
  if (i < n) out[i] = s[t] - v;
  if (t == 255) part[blockIdx.x] = s[255];
}

__global__ void scan2(int* __restrict__ part, int nb) {
  __shared__ int s[256];
  __shared__ int carry;
  int t = threadIdx.x;
  if (t == 0) carry = 0;
  __syncthreads();
  for (int base = 0; base < nb; base += 256) {
    int i = base + t;
    int v = (i < nb) ? part[i] : 0;
    s[t] = v;
    __syncthreads();
    for (int off = 1; off < 256; off <<= 1) {
      int tmp = (t >= off) ? s[t - off] : 0;
      __syncthreads();
      s[t] += tmp;
      __syncthreads();
    }
    if (i < nb) part[i] = s[t] - v + carry;
    __syncthreads();
    if (t == 255) carry += s[255];
    __syncthreads();
  }
}

__global__ void scan3(int* __restrict__ out, const int* __restrict__ part, int n) {
  int i = blockIdx.x * 256 + threadIdx.x;
  if (i < n) out[i] += part[blockIdx.x];
}

// ---------------------------------------------------------------- range-partitioned fill
// FG node-ranges x FR edge-slices. All FR slice-blocks of a range share an XCD
// (bid&7 heuristic) so each range's output region assembles full lines in ONE L2.
#define FG 128
#define FR 8
__global__ __launch_bounds__(256) void fill_ranged(
    const int* __restrict__ src, const int* __restrict__ dst,
    const int* __restrict__ ls, const int* __restrict__ ld,
    const int* __restrict__ off_t, const int* __restrict__ off_e,
    const int* __restrict__ off_l,
    int* __restrict__ cnt_t, int* __restrict__ cnt_e, int* __restrict__ cnt_l,
    int* __restrict__ adj_t, int* __restrict__ adj_e_m,
    long long* __restrict__ lpair_m, int E, int L, int n_t, int n_e) {
  const int bid = blockIdx.x;
  const int xcd = bid & 7;
  const int j = bid >> 3;                  // 0..127
  const int range = xcd * (FG / 8) + (j & (FG / 8 - 1));
  const int slice = j >> 4;                // 0..FR-1
  const int Tt = (n_t + FG - 1) / FG;
  const int Te = (n_e + FG - 1) / FG;
  const int t0 = range * Tt, t1 = min(n_t, t0 + Tt);
  const int e0 = range * Te, e1 = min(n_e, e0 + Te);
  const int tid = threadIdx.x;

  // edges slice
  const int ce = (E + FR - 1) / FR;
  const int i0 = slice * ce, i1 = min(E, i0 + ce);
  for (int i = i0 + tid; i < i1; i += 256) {
    int s = src[i], d = dst[i];
    if (d >= t0 && d < t1) {
      int p = off_t[d] + atomicSub(&cnt_t[d], 1) - 1;
      adj_t[p] = s;
    }
    if (s >= e0 && s < e1) {
      int p = off_e[s] + atomicSub(&cnt_e[s], 1) - 1;
      adj_e_m[p] = d;
    }
  }
  // labels slice
  const int cl = (L + FR - 1) / FR;
  const int l0 = slice * cl, l1 = min(L, l0 + cl);
  for (int i = l0 + tid; i < l1; i += 256) {
    int d = ld[i];
    if (d >= t0 && d < t1) {
      int p = off_l[d] + atomicSub(&cnt_l[d], 1) - 1;
      lpair_m[p] = ((long long)ls[i] << 32) | (unsigned int)i;
    }
  }
}

// ---------------------------------------------------------------- dual pull mean (bf16 feats)
__global__ void pull_mean_dual(
    const ushort_t* __restrict__ featA, const int* __restrict__ offA, const int* __restrict__ adjA,
    ushort_t* __restrict__ outA, int nA,
    const ushort_t* __restrict__ featB, const int* __restrict__ offB, const int* __restrict__ adjB,
    ushort_t* __restrict__ outB, int nB) {
  int gid = blockIdx.x * blockDim.x + threadIdx.x;
  int wave = gid >> 6;
  int lane = gid & 63;
  int nw = (gridDim.x * blockDim.x) >> 6;
  for (int v = wave; v < nA + nB; v += nw) {
    const uint_t* f;
    const int* off;
    const int* adj;
    uint_t* o;
    int vv;
    if (v < nA) {
      f = (const uint_t*)featA; off = offA; adj = adjA; o = (uint_t*)outA; vv = v;
    } else {
      f = (const uint_t*)featB; off = offB; adj = adjB; o = (uint_t*)outB; vv = v - nA;
    }
    int s = off[vv], e = off[vv + 1];
    float ax0 = 0.f, ay0 = 0.f, ax1 = 0.f, ay1 = 0.f;
    float ax2 = 0.f, ay2 = 0.f, ax3 = 0.f, ay3 = 0.f;
    int i = s;
    for (; i + 4 <= e; i += 4) {
      uint_t u0 = f[(size_t)adj[i] * 64 + lane];
      uint_t u1 = f[(size_t)adj[i + 1] * 64 + lane];
      uint_t u2 = f[(size_t)adj[i + 2] * 64 + lane];
      uint_t u3 = f[(size_t)adj[i + 3] * 64 + lane];
      ax0 += bflo(u0); ay0 += bfhi(u0);
      ax1 += bflo(u1); ay1 += bfhi(u1);
      ax2 += bflo(u2); ay2 += bfhi(u2);
      ax3 += bflo(u3); ay3 += bfhi(u3);
    }
    for (; i < e; ++i) {
      uint_t u = f[(size_t)adj[i] * 64 + lane];
      ax0 += bflo(u); ay0 += bfhi(u);
    }
    float rd = 1.0f / fmaxf((float)(e - s), 1.0f);
    o[(size_t)vv * 64 + lane] =
        (uint_t)f2bf(((ax0 + ax1) + (ax2 + ax3)) * rd) |
        ((uint_t)f2bf(((ay0 + ay1) + (ay2 + ay3)) * rd) << 16);
  }
}

// ---------------------------------------------------------------- dual MFMA GEMM
template <bool RELU>
__global__ __launch_bounds__(256, 2) void gemm_mfma_dual(
    const ushort_t* __restrict__ aggA, const ushort_t* __restrict__ xdA,
    const ushort_t* __restrict__ wfA, const float* __restrict__ biasA,
    ushort_t* __restrict__ outA, int nA, int gA,
    const ushort_t* __restrict__ aggB, const ushort_t* __restrict__ xdB,
    const ushort_t* __restrict__ wfB, const float* __restrict__ biasB,
    ushort_t* __restrict__ outB, int nB) {
  __shared__ __align__(16) ushort_t sA[64 * 128];
  __shared__ __align__(16) ushort_t sX[64 * 128];
  const ushort_t *agg, *xd, *wfrag;
  const float* bias;
  ushort_t* outp;
  int n, b0, nbl;
  if ((int)blockIdx.x < gA) {
    agg = aggA; xd = xdA; wfrag = wfA; bias = biasA; outp = outA; n = nA;
    b0 = blockIdx.x; nbl = gA;
  } else {
    agg = aggB; xd = xdB; wfrag = wfB; bias = biasB; outp = outB; n = nB;
    b0 = blockIdx.x - gA; nbl = gridDim.x - gA;
  }
  const int t = threadIdx.x;
  const int lane = t & 63;
  const int wid = t >> 6;
  const int mrow = (wid >> 1) * 32;
  const int nhalf = (wid & 1) * 64;

  s16x8 B[8][4];
#pragma unroll
  for (int ks = 0; ks < 8; ++ks)
#pragma unroll
    for (int nfi = 0; nfi < 4; ++nfi)
      B[ks][nfi] = *(const s16x8*)(wfrag + (size_t)(((ks << 3) | ((nhalf >> 4) + nfi)) << 9) + (lane << 3));

  float bv[4];
#pragma unroll
  for (int nfi = 0; nfi < 4; ++nfi) bv[nfi] = bias[nhalf + nfi * 16 + (lane & 15)];

  const int lrow = lane >> 4;
  const int pbyte = (lane & 15) << 4;

  const int ntiles = (n + 63) >> 6;
  for (int tile = b0; tile < ntiles; tile += nbl) {
    const int row0 = tile << 6;
#pragma unroll
    for (int i = 0; i < 8; ++i) {
      int reg = (wid << 3) + i;
      int rr = ((reg & 15) << 2) + lrow;
      int row = row0 + rr;
      row = row < n ? row : n - 1;
      int pp = pbyte ^ ((rr & 7) << 4);
      const ushort_t* srcp = (reg < 16 ? agg : xd) + (size_t)row * H + (pp >> 1);
      ushort_t* ldst = (reg < 16 ? sA : sX) + ((reg & 15) << 9);
      gload_lds16(srcp, ldst);
    }
    __syncthreads();

    f32x4 acc[2][4];
#pragma unroll
    for (int mi = 0; mi < 2; ++mi)
#pragma unroll
      for (int nfi = 0; nfi < 4; ++nfi) {
        f32x4 c = {bv[nfi], bv[nfi], bv[nfi], bv[nfi]};
        acc[mi][nfi] = c;
      }

    const int rr0 = mrow + (lane & 15);
    const int rr1 = rr0 + 16;
    const int kx = (lane >> 4) << 4;
    const int sw = (rr0 & 7) << 4;
#pragma unroll
    for (int ks = 0; ks < 8; ++ks) {
      const ushort_t* base = (ks < 4) ? sA : sX;
      const int kb = (ks & 3) << 6;
      s16x8 a0 = *(const s16x8*)((const char*)base + rr0 * 256 + ((kb | kx) ^ sw));
      s16x8 a1 = *(const s16x8*)((const char*)base + rr1 * 256 + ((kb | kx) ^ sw));
#pragma unroll
      for (int nfi = 0; nfi < 4; ++nfi) {
        acc[0][nfi] = __builtin_amdgcn_mfma_f32_16x16x32_bf16(a0, B[ks][nfi], acc[0][nfi], 0, 0, 0);
        acc[1][nfi] = __builtin_amdgcn_mfma_f32_16x16x32_bf16(a1, B[ks][nfi], acc[1][nfi], 0, 0, 0);
      }
    }

#pragma unroll
    for (int mi = 0; mi < 2; ++mi) {
      int rbase = row0 + mrow + mi * 16 + ((lane >> 4) << 2);
#pragma unroll
      for (int r = 0; r < 4; ++r) {
        int row = rbase + r;
        if (row < n) {
#pragma unroll
          for (int nfi = 0; nfi < 4; ++nfi) {
            float v = acc[mi][nfi][r];
            if (RELU) v = fmaxf(v, 0.f);
            outp[(size_t)row * H + nhalf + nfi * 16 + (lane & 15)] = f2bf(v);
          }
        }
      }
    }
    __syncthreads();
  }
}

// ---------------------------------------------------------------- grouped edge dot
__global__ void edge_dot_grouped(const ushort_t* __restrict__ ze, const ushort_t* __restrict__ zt,
                                 const int* __restrict__ loff, const long long* __restrict__ lpair,
                                 float* __restrict__ out, int n_t) {
  int gid = blockIdx.x * blockDim.x + threadIdx.x;
  int wave = gid >> 6;
  int lane = gid & 63;
  int nw = (gridDim.x * blockDim.x) >> 6;
  const uint_t* fz = (const uint_t*)ze;
  const uint_t* ft = (const uint_t*)zt;
  for (int v = wave; v < n_t; v += nw) {
    int s = loff[v], e = loff[v + 1];
    if (s == e) continue;
    uint_t ub = ft[(size_t)v * 64 + lane];
    float blo = bflo(ub), bhi = bfhi(ub);
    int i = s;
    for (; i + 4 <= e; i += 4) {
      long long q0 = lpair[i], q1 = lpair[i + 1], q2 = lpair[i + 2], q3 = lpair[i + 3];
      uint_t u0 = fz[(size_t)(int)(q0 >> 32) * 64 + lane];
      uint_t u1 = fz[(size_t)(int)(q1 >> 32) * 64 + lane];
      uint_t u2 = fz[(size_t)(int)(q2 >> 32) * 64 + lane];
      uint_t u3 = fz[(size_t)(int)(q3 >> 32) * 64 + lane];
      float p0 = bflo(u0) * blo + bfhi(u0) * bhi;
      float p1 = bflo(u1) * blo + bfhi(u1) * bhi;
      float p2 = bflo(u2) * blo + bfhi(u2) * bhi;
      float p3 = bflo(u3) * blo + bfhi(u3) * bhi;
#pragma unroll
      for (int o = 32; o; o >>= 1) {
        p0 += __shfl_down(p0, o);
        p1 += __shfl_down(p1, o);
        p2 += __shfl_down(p2, o);
        p3 += __shfl_down(p3, o);
      }
      if (lane == 0) {
        __builtin_nontemporal_store(p0, &out[(int)q0]);
        __builtin_nontemporal_store(p1, &out[(int)q1]);
        __builtin_nontemporal_store(p2, &out[(int)q2]);
        __builtin_nontemporal_store(p3, &out[(int)q3]);
      }
    }
    for (; i < e; ++i) {
      long long q0 = lpair[i];
      uint_t u0 = fz[(size_t)(int)(q0 >> 32) * 64 + lane];
      float p0 = bflo(u0) * blo + bfhi(u0) * bhi;
#pragma unroll
      for (int o = 32; o; o >>= 1) p0 += __shfl_down(p0, o);
      if (lane == 0) __builtin_nontemporal_store(p0, &out[(int)q0]);
    }
  }
}

// ---------------------------------------------------------------- launch
extern "C" void kernel_launch(void* const* d_in, const int* in_sizes, int n_in,
                              void* d_out, int out_size, void* d_ws, size_t ws_size,
                              hipStream_t stream) {
  const float* x_e = (const float*)d_in[0];
  const float* x_t = (const float*)d_in[1];
  const int* src = (const int*)d_in[2];
  const int* dst = (const int*)d_in[3];
  const int* ls = (const int*)d_in[4];
  const int* ld = (const int*)d_in[5];
  const float* W1et_l = (const float*)d_in[6];
  const float* W1et_r = (const float*)d_in[7];
  const float* W1te_l = (const float*)d_in[8];
  const float* W1te_r = (const float*)d_in[9];
  const float* W2et_l = (const float*)d_in[10];
  const float* W2et_r = (const float*)d_in[11];
  const float* W2te_l = (const float*)d_in[12];
  const float* W2te_r = (const float*)d_in[13];
  const float* b1et = (const float*)d_in[14];
  const float* b1te = (const float*)d_in[15];
  const float* b2et = (const float*)d_in[16];
  const float* b2te = (const float*)d_in[17];

  const int n_e = in_sizes[0] / H;
  const int n_t = in_sizes[1] / H;
  const int E = in_sizes[2];
  const int L = in_sizes[4];
  float* out = (float*)d_out;

  const size_t fe = (size_t)n_e * H;
  const size_t ft = (size_t)n_t * H;
  ushort_t* us = (ushort_t*)d_ws;
  ushort_t* xb_e = us;               // fe
  ushort_t* xb_t = xb_e + fe;        // ft  (contiguous with xb_e for cvt2)
  ushort_t* agg_e = xb_t + ft;       // fe  (layer2: z_expert in place)
  ushort_t* agg_t = agg_e + fe;      // ft  (… z_team in place)
  ushort_t* h_e = agg_t + ft;        // fe
  ushort_t* h_t = h_e + fe;          // ft
  ushort_t* wfrag = h_t + ft;        // 4*32768 (order: 1et, 1te, 2et, 2te)
  int* ib = (int*)(wfrag + 4 * 32768);
  const int Mt = n_t + 1, Me = n_e + 1, Ml = n_t + 1;
  const int M = Mt + Me + Ml;
  int* cnt = ib;               // M   ([cnt_t | cnt_e | cnt_l])
  int* off = cnt + M;          // M   ([off_t | off_e(+E) | off_l(+2E)])
  int* part = off + M;         // 1024
  int* adj_t = part + 1024;    // E
  int* adj_e = adj_t + E;      // E
  long long* lpair = (long long*)(((unsigned long long)(adj_e + E) + 7) & ~7ULL);  // L x 8B

  int* cnt_t = cnt;
  int* cnt_e = cnt + Mt;
  int* cnt_l = cnt + Mt + Me;
  int* off_t = off;
  int* off_e = off + Mt;            // values in [E, 2E]
  int* off_l = off + Mt + Me;       // values in [2E, 2E+L]
  int* adj_e_m = adj_e - E;
  long long* lpair_m = lpair - 2 * (size_t)E;

  const dim3 blk(256);

  // ---- conversions + weight fragments
  cvt2_bf16<<<2048, blk, 0, stream>>>(x_e, x_t, fe / 4, (fe + ft) / 4, (uint2*)xb_e);
  build_wfrag4<<<512, blk, 0, stream>>>(W1et_l, W1et_r, W1te_l, W1te_r,
                                        W2et_l, W2et_r, W2te_l, W2te_r, wfrag);

  // ---- merged CSR build (edges + labels), single concatenated scan
  zero_i32<<<256, blk, 0, stream>>>(cnt, M);
  hist_all<<<1024, blk, 0, stream>>>(src, dst, ld, cnt_t, cnt_e, cnt_l, E, L);
  int nb = (M + 255) / 256;
  scan1<<<nb, blk, 0, stream>>>(cnt, off, part, M);
  scan2<<<1, blk, 0, stream>>>(part, nb);
  scan3<<<nb, blk, 0, stream>>>(off, part, M);
  fill_ranged<<<FG * FR, blk, 0, stream>>>(src, dst, ls, ld, off_t, off_e, off_l,
                                           cnt_t, cnt_e, cnt_l,
                                           adj_t, adj_e_m, lpair_m, E, L, n_t, n_e);

  const int gt = (n_t + 63) / 64, ge = (n_e + 63) / 64;
  const int gA = min(gt, 512), gB = min(ge, 512);
  const int npull = ((n_t + n_e) + 3) / 4;

  // ---- layer 1
  pull_mean_dual<<<npull, blk, 0, stream>>>(xb_e, off_t, adj_t, agg_t, n_t,
                                            xb_t, off_e, adj_e_m, agg_e, n_e);
  gemm_mfma_dual<true><<<gA + gB, blk, 0, stream>>>(
      agg_t, xb_t, wfrag + 0 * 32768, b1et, h_t, n_t, gA,
      agg_e, xb_e, wfrag + 1 * 32768, b1te, h_e, n_e);

  // ---- layer 2 (z written in place over agg)
  pull_mean_dual<<<npull, blk, 0, stream>>>(h_e, off_t, adj_t, agg_t, n_t,
                                            h_t, off_e, adj_e_m, agg_e, n_e);
  gemm_mfma_dual<false><<<gA + gB, blk, 0, stream>>>(
      agg_t, h_t, wfrag + 2 * 32768, b2et, agg_t, n_t, gA,
      agg_e, h_e, wfrag + 3 * 32768, b2te, agg_e, n_e);

  // ---- grouped edge dot readout
  edge_dot_grouped<<<(n_t + 3) / 4, blk, 0, stream>>>(agg_e, agg_t, off_l, lpair_m, out, n_t);
}

// Round 8
// 359.053 us; speedup vs baseline: 1.9275x; 1.9275x over previous
//
#include <hip/hip_runtime.h>

#define H 128
typedef unsigned short ushort_t;
typedef unsigned int uint_t;
typedef unsigned long long u64_t;
using s16x8 = __attribute__((ext_vector_type(8))) short;
using f32x4 = __attribute__((ext_vector_type(4))) float;

// ---------------------------------------------------------------- bf16 helpers
__device__ __forceinline__ ushort_t f2bf(float x) {  // RNE
  uint_t u = __float_as_uint(x);
  return (ushort_t)((u + 0x7fff + ((u >> 16) & 1)) >> 16);
}
__device__ __forceinline__ float bflo(uint_t u) { return __uint_as_float(u << 16); }
__device__ __forceinline__ float bfhi(uint_t u) { return __uint_as_float(u & 0xffff0000u); }

// ---------------------------------------------------------------- async global->LDS 16B
__device__ __forceinline__ void gload_lds16(const void* g, void* l) {
  __builtin_amdgcn_global_load_lds(
      (const __attribute__((address_space(1))) unsigned int*)(unsigned long long)g,
      (__attribute__((address_space(3))) unsigned int*)(unsigned int)(unsigned long long)l,
      16, 0, 0);
}

// ---------------------------------------------------------------- zero ints
__global__ void zero_i32(int* __restrict__ p, int n) {
  int i = blockIdx.x * blockDim.x + threadIdx.x;
  int s = gridDim.x * blockDim.x;
  for (; i < n; i += s) p[i] = 0;
}

// ---------------------------------------------------------------- fp32 -> bf16 (two srcs, contiguous dst)
__global__ void cvt2_bf16(const float* __restrict__ a, const float* __restrict__ b,
                          size_t n4a, size_t n4tot, uint2* __restrict__ out) {
  size_t i = (size_t)blockIdx.x * blockDim.x + threadIdx.x;
  size_t s = (size_t)gridDim.x * blockDim.x;
  for (; i < n4tot; i += s) {
    float4 v = (i < n4a) ? ((const float4*)a)[i] : ((const float4*)b)[i - n4a];
    uint2 r;
    r.x = (uint_t)f2bf(v.x) | ((uint_t)f2bf(v.y) << 16);
    r.y = (uint_t)f2bf(v.z) | ((uint_t)f2bf(v.w) << 16);
    out[i] = r;
  }
}

// ------------------------------------------- 4 W-pairs -> MFMA B-fragment layout
__global__ void build_wfrag4(const float* __restrict__ Wl0, const float* __restrict__ Wr0,
                             const float* __restrict__ Wl1, const float* __restrict__ Wr1,
                             const float* __restrict__ Wl2, const float* __restrict__ Wr2,
                             const float* __restrict__ Wl3, const float* __restrict__ Wr3,
                             ushort_t* __restrict__ dst) {
  int i = blockIdx.x * 256 + threadIdx.x;  // 0..131071
  int w = i >> 15;
  int ii = i & 32767;
  int j = ii & 7;
  int lane = (ii >> 3) & 63;
  int nf = (ii >> 9) & 7;
  int ks = ii >> 12;
  int k = ks * 32 + (lane >> 4) * 8 + j;
  int nn = nf * 16 + (lane & 15);
  const float* Wl = (w == 0) ? Wl0 : (w == 1) ? Wl1 : (w == 2) ? Wl2 : Wl3;
  const float* Wr = (w == 0) ? Wr0 : (w == 1) ? Wr1 : (w == 2) ? Wr2 : Wr3;
  float v = (k < H) ? Wl[k * H + nn] : Wr[(k - H) * H + nn];
  dst[i] = f2bf(v);
}

// ---------------------------------------------------------------- merged histogram (edges + labels)
__global__ void hist_all(const int* __restrict__ src, const int* __restrict__ dst,
                         const int* __restrict__ ld,
                         int* __restrict__ cnt_t, int* __restrict__ cnt_e,
                         int* __restrict__ cnt_l, int E, int L) {
  int i = blockIdx.x * blockDim.x + threadIdx.x;
  int s = gridDim.x * blockDim.x;
  int M = E > L ? E : L;
  for (; i < M; i += s) {
    if (i < E) {
      atomicAdd(&cnt_t[dst[i]], 1);
      atomicAdd(&cnt_e[src[i]], 1);
    }
    if (i < L) atomicAdd(&cnt_l[ld[i]], 1);
  }
}

// ---------------------------------------------------------------- 3-phase exclusive scan
__global__ void scan1(const int* __restrict__ in, int* __restrict__ out,
                      int* __restrict__ part, int n) {
  __shared__ int s[256];
  int t = threadIdx.x;
  int i = blockIdx.x * 256 + t;
  int v = (i < n) ? in[i] : 0;
  s[t] = v;
  __syncthreads();
  for (int off = 1; off < 256; off <<= 1) {
    int tmp = (t >= off) ? s[t - off] : 0;
    __syncthreads();
    s[t] += tmp;
    __syncthreads();
  }
  if (i < n) out[i] = s[t] - v;
  if (t == 255) part[blockIdx.x] = s[255];
}

__global__ void scan2(int* __restrict__ part, int nb) {
  __shared__ int s[256];
  __shared__ int carry;
  int t = threadIdx.x;
  if (t == 0) carry = 0;
  __syncthreads();
  for (int base = 0; base < nb; base += 256) {
    int i = base + t;
    int v = (i < nb) ? part[i] : 0;
    s[t] = v;
    __syncthreads();
    for (int off = 1; off < 256; off <<= 1) {
      int tmp = (t >= off) ? s[t - off] : 0;
      __syncthreads();
      s[t] += tmp;
      __syncthreads();
    }
    if (i < nb) part[i] = s[t] - v + carry;
    __syncthreads();
    if (t == 255) carry += s[255];
    __syncthreads();
  }
}

__global__ void scan3(int* __restrict__ out, const int* __restrict__ part, int n) {
  int i = blockIdx.x * 256 + threadIdx.x;
  if (i < n) out[i] += part[blockIdx.x];
}

// ---------------------------------------------------------------- bucket cursor init
// bucket b of stream covers nodes [b<<shift, (b+1)<<shift); cursor starts at off[b<<shift]
__global__ void init_cur(const int* __restrict__ off_t, const int* __restrict__ off_e,
                         const int* __restrict__ off_l,
                         int* __restrict__ cur_t, int* __restrict__ cur_e,
                         int* __restrict__ cur_l, int n_t, int n_e, int NBt, int NBe) {
  int j = threadIdx.x;
  if (j < NBt) cur_t[j] = off_t[min(n_t, j << 8)];
  if (j < NBe) cur_e[j] = off_e[min(n_e, j << 9)];
  if (j < NBt) cur_l[j] = off_l[min(n_t, j << 8)];
}

// ---------------------------------------------------------------- pass 1: radix bucket scatter
// chunk-per-block; LDS histogram -> one global atomicAdd per (block,bucket) -> segment writes.
#define CH 4096
__global__ __launch_bounds__(256) void bucket_scatter(
    const int* __restrict__ src, const int* __restrict__ dst,
    const int* __restrict__ ls, const int* __restrict__ ld,
    int* __restrict__ cur_t, int* __restrict__ cur_e, int* __restrict__ cur_l,
    u64_t* __restrict__ pairs_t, u64_t* __restrict__ pairs_e_m, u64_t* __restrict__ pairs_l_m,
    int E, int L, int nct, int nce) {
  __shared__ int hist[256];
  __shared__ int start[256];
  int b = blockIdx.x;
  const int tid = threadIdx.x;
  int stream, i0, n;
  if (b < nct) { stream = 0; i0 = b * CH; n = E; }
  else if (b < nct + nce) { stream = 1; i0 = (b - nct) * CH; n = E; }
  else { stream = 2; i0 = (b - nct - nce) * CH; n = L; }
  const int i1 = min(n, i0 + CH);

  hist[tid] = 0;
  __syncthreads();
  for (int i = i0 + tid; i < i1; i += 256) {
    int d = (stream == 0) ? dst[i] : (stream == 1) ? src[i] : ld[i];
    int bkt = (stream == 1) ? (d >> 9) : (d >> 8);
    atomicAdd(&hist[bkt], 1);
  }
  __syncthreads();
  int* cur = (stream == 0) ? cur_t : (stream == 1) ? cur_e : cur_l;
  int h = hist[tid];
  if (h) start[tid] = atomicAdd(&cur[tid], h);
  __syncthreads();
  for (int i = i0 + tid; i < i1; i += 256) {
    u64_t rec;
    int bkt;
    u64_t* pp;
    if (stream == 0) {
      int d = dst[i];
      rec = ((u64_t)d << 32) | (uint_t)src[i];
      bkt = d >> 8;
      pp = pairs_t;
    } else if (stream == 1) {
      int d = src[i];
      rec = ((u64_t)d << 32) | (uint_t)dst[i];
      bkt = d >> 9;
      pp = pairs_e_m;
    } else {
      int d = ld[i];
      rec = ((u64_t)d << 40) | ((u64_t)(uint_t)ls[i] << 20) | (uint_t)i;  // d:24|ls:20|i:20
      bkt = d >> 8;
      pp = pairs_l_m;
    }
    int pos = start[bkt] + atomicSub(&hist[bkt], 1) - 1;
    pp[pos] = rec;
  }
}

// ---------------------------------------------------------------- pass 2: in-bucket place
// one block per bucket; per-node cursors in LDS; scattered stores confined to ~12KB region.
__global__ __launch_bounds__(256) void place_all(
    const u64_t* __restrict__ pairs_t, const u64_t* __restrict__ pairs_e_m,
    const u64_t* __restrict__ pairs_l_m,
    const int* __restrict__ off_t, const int* __restrict__ off_e, const int* __restrict__ off_l,
    int* __restrict__ adj_t, int* __restrict__ adj_e_m, long long* __restrict__ lpair_m,
    int n_t, int n_e, int NBt, int NBe) {
  __shared__ int curs[513];
  int b = blockIdx.x;
  const int tid = threadIdx.x;
  int stream, d0, d1;
  const int* off;
  if (b < NBt) { stream = 0; d0 = b << 8; d1 = min(n_t, d0 + 256); off = off_t; }
  else if (b < NBt + NBe) { stream = 1; d0 = (b - NBt) << 9; d1 = min(n_e, d0 + 512); off = off_e; }
  else { stream = 2; d0 = (b - NBt - NBe) << 8; d1 = min(n_t, d0 + 256); off = off_l; }
  const int nn = d1 - d0;
  for (int k = tid; k < nn; k += 256) curs[k] = off[d0 + k];
  __syncthreads();
  const int rs = off[d0], re = off[d1];
  if (stream == 0) {
    for (int i = rs + tid; i < re; i += 256) {
      u64_t rec = pairs_t[i];
      int d = (int)(rec >> 32), s = (int)rec;
      adj_t[atomicAdd(&curs[d - d0], 1)] = s;
    }
  } else if (stream == 1) {
    for (int i = rs + tid; i < re; i += 256) {
      u64_t rec = pairs_e_m[i];
      int d = (int)(rec >> 32), s = (int)rec;
      adj_e_m[atomicAdd(&curs[d - d0], 1)] = s;
    }
  } else {
    for (int i = rs + tid; i < re; i += 256) {
      u64_t rec = pairs_l_m[i];
      int d = (int)(rec >> 40);
      int lsv = (int)((rec >> 20) & 0xFFFFF);
      int li = (int)(rec & 0xFFFFF);
      lpair_m[atomicAdd(&curs[d - d0], 1)] = ((long long)lsv << 32) | (uint_t)li;
    }
  }
}

// ---------------------------------------------------------------- dual pull mean (bf16 feats)
__global__ void pull_mean_dual(
    const ushort_t* __restrict__ featA, const int* __restrict__ offA, const int* __restrict__ adjA,
    ushort_t* __restrict__ outA, int nA,
    const ushort_t* __restrict__ featB, const int* __restrict__ offB, const int* __restrict__ adjB,
    ushort_t* __restrict__ outB, int nB) {
  int gid = blockIdx.x * blockDim.x + threadIdx.x;
  int wave = gid >> 6;
  int lane = gid & 63;
  int nw = (gridDim.x * blockDim.x) >> 6;
  for (int v = wave; v < nA + nB; v += nw) {
    const uint_t* f;
    const int* off;
    const int* adj;
    uint_t* o;
    int vv;
    if (v < nA) {
      f = (const uint_t*)featA; off = offA; adj = adjA; o = (uint_t*)outA; vv = v;
    } else {
      f = (const uint_t*)featB; off = offB; adj = adjB; o = (uint_t*)outB; vv = v - nA;
    }
    int s = off[vv], e = off[vv + 1];
    float ax0 = 0.f, ay0 = 0.f, ax1 = 0.f, ay1 = 0.f;
    float ax2 = 0.f, ay2 = 0.f, ax3 = 0.f, ay3 = 0.f;
    int i = s;
    for (; i + 4 <= e; i += 4) {
      uint_t u0 = f[(size_t)adj[i] * 64 + lane];
      uint_t u1 = f[(size_t)adj[i + 1] * 64 + lane];
      uint_t u2 = f[(size_t)adj[i + 2] * 64 + lane];
      uint_t u3 = f[(size_t)adj[i + 3] * 64 + lane];
      ax0 += bflo(u0); ay0 += bfhi(u0);
      ax1 += bflo(u1); ay1 += bfhi(u1);
      ax2 += bflo(u2); ay2 += bfhi(u2);
      ax3 += bflo(u3); ay3 += bfhi(u3);
    }
    for (; i < e; ++i) {
      uint_t u = f[(size_t)adj[i] * 64 + lane];
      ax0 += bflo(u); ay0 += bfhi(u);
    }
    float rd = 1.0f / fmaxf((float)(e - s), 1.0f);
    o[(size_t)vv * 64 + lane] =
        (uint_t)f2bf(((ax0 + ax1) + (ax2 + ax3)) * rd) |
        ((uint_t)f2bf(((ay0 + ay1) + (ay2 + ay3)) * rd) << 16);
  }
}

// ---------------------------------------------------------------- dual MFMA GEMM
template <bool RELU>
__global__ __launch_bounds__(256, 2) void gemm_mfma_dual(
    const ushort_t* __restrict__ aggA, const ushort_t* __restrict__ xdA,
    const ushort_t* __restrict__ wfA, const float* __restrict__ biasA,
    ushort_t* __restrict__ outA, int nA, int gA,
    const ushort_t* __restrict__ aggB, const ushort_t* __restrict__ xdB,
    const ushort_t* __restrict__ wfB, const float* __restrict__ biasB,
    ushort_t* __restrict__ outB, int nB) {
  __shared__ __align__(16) ushort_t sA[64 * 128];
  __shared__ __align__(16) ushort_t sX[64 * 128];
  const ushort_t *agg, *xd, *wfrag;
  const float* bias;
  ushort_t* outp;
  int n, b0, nbl;
  if ((int)blockIdx.x < gA) {
    agg = aggA; xd = xdA; wfrag = wfA; bias = biasA; outp = outA; n = nA;
    b0 = blockIdx.x; nbl = gA;
  } else {
    agg = aggB; xd = xdB; wfrag = wfB; bias = biasB; outp = outB; n = nB;
    b0 = blockIdx.x - gA; nbl = gridDim.x - gA;
  }
  const int t = threadIdx.x;
  const int lane = t & 63;
  const int wid = t >> 6;
  const int mrow = (wid >> 1) * 32;
  const int nhalf = (wid & 1) * 64;

  s16x8 B[8][4];
#pragma unroll
  for (int ks = 0; ks < 8; ++ks)
#pragma unroll
    for (int nfi = 0; nfi < 4; ++nfi)
      B[ks][nfi] = *(const s16x8*)(wfrag + (size_t)(((ks << 3) | ((nhalf >> 4) + nfi)) << 9) + (lane << 3));

  float bv[4];
#pragma unroll
  for (int nfi = 0; nfi < 4; ++nfi) bv[nfi] = bias[nhalf + nfi * 16 + (lane & 15)];

  const int lrow = lane >> 4;
  const int pbyte = (lane & 15) << 4;

  const int ntiles = (n + 63) >> 6;
  for (int tile = b0; tile < ntiles; tile += nbl) {
    const int row0 = tile << 6;
#pragma unroll
    for (int i = 0; i < 8; ++i) {
      int reg = (wid << 3) + i;
      int rr = ((reg & 15) << 2) + lrow;
      int row = row0 + rr;
      row = row < n ? row : n - 1;
      int pp = pbyte ^ ((rr & 7) << 4);
      const ushort_t* srcp = (reg < 16 ? agg : xd) + (size_t)row * H + (pp >> 1);
      ushort_t* ldst = (reg < 16 ? sA : sX) + ((reg & 15) << 9);
      gload_lds16(srcp, ldst);
    }
    __syncthreads();

    f32x4 acc[2][4];
#pragma unroll
    for (int mi = 0; mi < 2; ++mi)
#pragma unroll
      for (int nfi = 0; nfi < 4; ++nfi) {
        f32x4 c = {bv[nfi], bv[nfi], bv[nfi], bv[nfi]};
        acc[mi][nfi] = c;
      }

    const int rr0 = mrow + (lane & 15);
    const int rr1 = rr0 + 16;
    const int kx = (lane >> 4) << 4;
    const int sw = (rr0 & 7) << 4;
#pragma unroll
    for (int ks = 0; ks < 8; ++ks) {
      const ushort_t* base = (ks < 4) ? sA : sX;
      const int kb = (ks & 3) << 6;
      s16x8 a0 = *(const s16x8*)((const char*)base + rr0 * 256 + ((kb | kx) ^ sw));
      s16x8 a1 = *(const s16x8*)((const char*)base + rr1 * 256 + ((kb | kx) ^ sw));
#pragma unroll
      for (int nfi = 0; nfi < 4; ++nfi) {
        acc[0][nfi] = __builtin_amdgcn_mfma_f32_16x16x32_bf16(a0, B[ks][nfi], acc[0][nfi], 0, 0, 0);
        acc[1][nfi] = __builtin_amdgcn_mfma_f32_16x16x32_bf16(a1, B[ks][nfi], acc[1][nfi], 0, 0, 0);
      }
    }

#pragma unroll
    for (int mi = 0; mi < 2; ++mi) {
      int rbase = row0 + mrow + mi * 16 + ((lane >> 4) << 2);
#pragma unroll
      for (int r = 0; r < 4; ++r) {
        int row = rbase + r;
        if (row < n) {
#pragma unroll
          for (int nfi = 0; nfi < 4; ++nfi) {
            float v = acc[mi][nfi][r];
            if (RELU) v = fmaxf(v, 0.f);
            outp[(size_t)row * H + nhalf + nfi * 16 + (lane & 15)] = f2bf(v);
          }
        }
      }
    }
    __syncthreads();
  }
}

// ---------------------------------------------------------------- grouped edge dot
__global__ void edge_dot_grouped(const ushort_t* __restrict__ ze, const ushort_t* __restrict__ zt,
                                 const int* __restrict__ loff, const long long* __restrict__ lpair,
                                 float* __restrict__ out, int n_t) {
  int gid = blockIdx.x * blockDim.x + threadIdx.x;
  int wave = gid >> 6;
  int lane = gid & 63;
  int nw = (gridDim.x * blockDim.x) >> 6;
  const uint_t* fz = (const uint_t*)ze;
  const uint_t* ft = (const uint_t*)zt;
  for (int v = wave; v < n_t; v += nw) {
    int s = loff[v], e = loff[v + 1];
    if (s == e) continue;
    uint_t ub = ft[(size_t)v * 64 + lane];
    float blo = bflo(ub), bhi = bfhi(ub);
    int i = s;
    for (; i + 4 <= e; i += 4) {
      long long q0 = lpair[i], q1 = lpair[i + 1], q2 = lpair[i + 2], q3 = lpair[i + 3];
      uint_t u0 = fz[(size_t)(int)(q0 >> 32) * 64 + lane];
      uint_t u1 = fz[(size_t)(int)(q1 >> 32) * 64 + lane];
      uint_t u2 = fz[(size_t)(int)(q2 >> 32) * 64 + lane];
      uint_t u3 = fz[(size_t)(int)(q3 >> 32) * 64 + lane];
      float p0 = bflo(u0) * blo + bfhi(u0) * bhi;
      float p1 = bflo(u1) * blo + bfhi(u1) * bhi;
      float p2 = bflo(u2) * blo + bfhi(u2) * bhi;
      float p3 = bflo(u3) * blo + bfhi(u3) * bhi;
#pragma unroll
      for (int o = 32; o; o >>= 1) {
        p0 += __shfl_down(p0, o);
        p1 += __shfl_down(p1, o);
        p2 += __shfl_down(p2, o);
        p3 += __shfl_down(p3, o);
      }
      if (lane == 0) {
        __builtin_nontemporal_store(p0, &out[(int)q0]);
        __builtin_nontemporal_store(p1, &out[(int)q1]);
        __builtin_nontemporal_store(p2, &out[(int)q2]);
        __builtin_nontemporal_store(p3, &out[(int)q3]);
      }
    }
    for (; i < e; ++i) {
      long long q0 = lpair[i];
      uint_t u0 = fz[(size_t)(int)(q0 >> 32) * 64 + lane];
      float p0 = bflo(u0) * blo + bfhi(u0) * bhi;
#pragma unroll
      for (int o = 32; o; o >>= 1) p0 += __shfl_down(p0, o);
      if (lane == 0) __builtin_nontemporal_store(p0, &out[(int)q0]);
    }
  }
}

// ---------------------------------------------------------------- launch
extern "C" void kernel_launch(void* const* d_in, const int* in_sizes, int n_in,
                              void* d_out, int out_size, void* d_ws, size_t ws_size,
                              hipStream_t stream) {
  const float* x_e = (const float*)d_in[0];
  const float* x_t = (const float*)d_in[1];
  const int* src = (const int*)d_in[2];
  const int* dst = (const int*)d_in[3];
  const int* ls = (const int*)d_in[4];
  const int* ld = (const int*)d_in[5];
  const float* W1et_l = (const float*)d_in[6];
  const float* W1et_r = (const float*)d_in[7];
  const float* W1te_l = (const float*)d_in[8];
  const float* W1te_r = (const float*)d_in[9];
  const float* W2et_l = (const float*)d_in[10];
  const float* W2et_r = (const float*)d_in[11];
  const float* W2te_l = (const float*)d_in[12];
  const float* W2te_r = (const float*)d_in[13];
  const float* b1et = (const float*)d_in[14];
  const float* b1te = (const float*)d_in[15];
  const float* b2et = (const float*)d_in[16];
  const float* b2te = (const float*)d_in[17];

  const int n_e = in_sizes[0] / H;
  const int n_t = in_sizes[1] / H;
  const int E = in_sizes[2];
  const int L = in_sizes[4];
  float* out = (float*)d_out;

  const size_t fe = (size_t)n_e * H;
  const size_t ft = (size_t)n_t * H;
  ushort_t* us = (ushort_t*)d_ws;
  ushort_t* xb_e = us;               // fe
  ushort_t* xb_t = xb_e + fe;        // ft  (contiguous with xb_e for cvt2)
  ushort_t* agg_e = xb_t + ft;       // fe  (layer2: z_expert in place)
  ushort_t* agg_t = agg_e + fe;      // ft  (… z_team in place)
  ushort_t* h_e = agg_t + ft;        // fe
  ushort_t* h_t = h_e + fe;          // ft
  ushort_t* wfrag = h_t + ft;        // 4*32768 (order: 1et, 1te, 2et, 2te)
  int* ib = (int*)(wfrag + 4 * 32768);
  const int Mt = n_t + 1, Me = n_e + 1, Ml = n_t + 1;
  const int M = Mt + Me + Ml;
  int* cnt = ib;               // M   ([cnt_t | cnt_e | cnt_l])
  int* off = cnt + M;          // M   ([off_t | off_e(+E) | off_l(+2E)])
  int* part = off + M;         // 1024
  int* adj_t = part + 1024;    // E
  int* adj_e = adj_t + E;      // E
  long long* lpair = (long long*)(((unsigned long long)(adj_e + E) + 7) & ~7ULL);  // L x 8B
  u64_t* pairs_t = (u64_t*)(lpair + L);   // E
  u64_t* pairs_e = pairs_t + E;           // E
  u64_t* pairs_l = pairs_e + E;           // L
  int* cur = (int*)(pairs_l + L);         // 768

  int* cnt_t = cnt;
  int* cnt_e = cnt + Mt;
  int* cnt_l = cnt + Mt + Me;
  int* off_t = off;
  int* off_e = off + Mt;            // values in [E, 2E]
  int* off_l = off + Mt + Me;       // values in [2E, 2E+L]
  int* adj_e_m = adj_e - E;
  long long* lpair_m = lpair - 2 * (size_t)E;
  u64_t* pairs_e_m = pairs_e - E;
  u64_t* pairs_l_m = pairs_l - 2 * (size_t)E;
  int* cur_t = cur;
  int* cur_e = cur + 256;
  int* cur_l = cur + 512;

  const int NBt = (n_t + 255) >> 8;   // teams: 256-node buckets
  const int NBe = (n_e + 511) >> 9;   // experts: 512-node buckets
  const int nct = (E + CH - 1) / CH;
  const int ncl = (L + CH - 1) / CH;

  const dim3 blk(256);

  // ---- conversions + weight fragments
  cvt2_bf16<<<2048, blk, 0, stream>>>(x_e, x_t, fe / 4, (fe + ft) / 4, (uint2*)xb_e);
  build_wfrag4<<<512, blk, 0, stream>>>(W1et_l, W1et_r, W1te_l, W1te_r,
                                        W2et_l, W2et_r, W2te_l, W2te_r, wfrag);

  // ---- merged CSR build (edges + labels): hist -> scan -> radix two-pass fill
  zero_i32<<<256, blk, 0, stream>>>(cnt, M);
  hist_all<<<1024, blk, 0, stream>>>(src, dst, ld, cnt_t, cnt_e, cnt_l, E, L);
  int nb = (M + 255) / 256;
  scan1<<<nb, blk, 0, stream>>>(cnt, off, part, M);
  scan2<<<1, blk, 0, stream>>>(part, nb);
  scan3<<<nb, blk, 0, stream>>>(off, part, M);
  init_cur<<<1, blk, 0, stream>>>(off_t, off_e, off_l, cur_t, cur_e, cur_l,
                                  n_t, n_e, NBt, NBe);
  bucket_scatter<<<nct + nct + ncl, blk, 0, stream>>>(
      src, dst, ls, ld, cur_t, cur_e, cur_l,
      pairs_t, pairs_e_m, pairs_l_m, E, L, nct, nct);
  place_all<<<NBt + NBe + NBt, blk, 0, stream>>>(
      pairs_t, pairs_e_m, pairs_l_m, off_t, off_e, off_l,
      adj_t, adj_e_m, lpair_m, n_t, n_e, NBt, NBe);

  const int gt = (n_t + 63) / 64, ge = (n_e + 63) / 64;
  const int gA = min(gt, 512), gB = min(ge, 512);
  const int npull = ((n_t + n_e) + 3) / 4;

  // ---- layer 1
  pull_mean_dual<<<npull, blk, 0, stream>>>(xb_e, off_t, adj_t, agg_t, n_t,
                                            xb_t, off_e, adj_e_m, agg_e, n_e);
  gemm_mfma_dual<true><<<gA + gB, blk, 0, stream>>>(
      agg_t, xb_t, wfrag + 0 * 32768, b1et, h_t, n_t, gA,
      agg_e, xb_e, wfrag + 1 * 32768, b1te, h_e, n_e);

  // ---- layer 2 (z written in place over agg)
  pull_mean_dual<<<npull, blk, 0, stream>>>(h_e, off_t, adj_t, agg_t, n_t,
                                            h_t, off_e, adj_e_m, agg_e, n_e);
  gemm_mfma_dual<false><<<gA + gB, blk, 0, stream>>>(
      agg_t, h_t, wfrag + 2 * 32768, b2et, agg_t, n_t, gA,
      agg_e, h_e, wfrag + 3 * 32768, b2te, agg_e, n_e);

  // ---- grouped edge dot readout
  edge_dot_grouped<<<(n_t + 3) / 4, blk, 0, stream>>>(agg_e, agg_t, off_l, lpair_m, out, n_t);
}

// Round 9
// 286.476 us; speedup vs baseline: 2.4159x; 1.2533x over previous
//
#include <hip/hip_runtime.h>

#define H 128
#define CH 4096
typedef unsigned short ushort_t;
typedef unsigned int uint_t;
typedef unsigned long long u64_t;
using s16x8 = __attribute__((ext_vector_type(8))) short;
using f32x4 = __attribute__((ext_vector_type(4))) float;

// ---------------------------------------------------------------- bf16 helpers
__device__ __forceinline__ ushort_t f2bf(float x) {  // RNE
  uint_t u = __float_as_uint(x);
  return (ushort_t)((u + 0x7fff + ((u >> 16) & 1)) >> 16);
}
__device__ __forceinline__ float bflo(uint_t u) { return __uint_as_float(u << 16); }
__device__ __forceinline__ float bfhi(uint_t u) { return __uint_as_float(u & 0xffff0000u); }

// ---------------------------------------------------------------- async global->LDS 16B
__device__ __forceinline__ void gload_lds16(const void* g, void* l) {
  __builtin_amdgcn_global_load_lds(
      (const __attribute__((address_space(1))) unsigned int*)(unsigned long long)g,
      (__attribute__((address_space(3))) unsigned int*)(unsigned int)(unsigned long long)l,
      16, 0, 0);
}

// ---------------------------------------------------------------- prologue (merged)
// blocks [0,2048): fp32->bf16 of x_e|x_t; [2048,2560): wfrag x4; [2560]: zero bcnt
__global__ __launch_bounds__(256) void prep_kernel(
    const float* __restrict__ xa, const float* __restrict__ xb,
    size_t n4a, size_t n4tot, uint2* __restrict__ xout,
    const float* __restrict__ Wl0, const float* __restrict__ Wr0,
    const float* __restrict__ Wl1, const float* __restrict__ Wr1,
    const float* __restrict__ Wl2, const float* __restrict__ Wr2,
    const float* __restrict__ Wl3, const float* __restrict__ Wr3,
    ushort_t* __restrict__ wdst, int* __restrict__ bcnt, int nbz) {
  const int b = blockIdx.x;
  const int tid = threadIdx.x;
  if (b < 2048) {
    size_t i = (size_t)b * 256 + tid;
    size_t s = 2048 * 256;
    for (; i < n4tot; i += s) {
      float4 v = (i < n4a) ? ((const float4*)xa)[i] : ((const float4*)xb)[i - n4a];
      uint2 r;
      r.x = (uint_t)f2bf(v.x) | ((uint_t)f2bf(v.y) << 16);
      r.y = (uint_t)f2bf(v.z) | ((uint_t)f2bf(v.w) << 16);
      xout[i] = r;
    }
  } else if (b < 2560) {
    int i = (b - 2048) * 256 + tid;  // 0..131071
    int w = i >> 15;
    int ii = i & 32767;
    int j = ii & 7;
    int lane = (ii >> 3) & 63;
    int nf = (ii >> 9) & 7;
    int ks = ii >> 12;
    int k = ks * 32 + (lane >> 4) * 8 + j;
    int nn = nf * 16 + (lane & 15);
    const float* Wl = (w == 0) ? Wl0 : (w == 1) ? Wl1 : (w == 2) ? Wl2 : Wl3;
    const float* Wr = (w == 0) ? Wr0 : (w == 1) ? Wr1 : (w == 2) ? Wr2 : Wr3;
    float v = (k < H) ? Wl[k * H + nn] : Wr[(k - H) * H + nn];
    wdst[i] = f2bf(v);
  } else {
    for (int i = tid; i < nbz; i += 256) bcnt[i] = 0;
  }
}

// ---------------------------------------------------------------- pass 0: bucket counts
__global__ __launch_bounds__(256) void bucket_count(
    const int* __restrict__ src, const int* __restrict__ dst, const int* __restrict__ ld,
    int* __restrict__ bcnt, int E, int L, int nct, int NBt, int NBe) {
  __shared__ int hist[256];
  const int b = blockIdx.x;
  const int tid = threadIdx.x;
  int stream, i0, n, base, shift;
  if (b < nct) { stream = 0; i0 = b * CH; n = E; base = 0; shift = 8; }
  else if (b < 2 * nct) { stream = 1; i0 = (b - nct) * CH; n = E; base = NBt; shift = 9; }
  else { stream = 2; i0 = (b - 2 * nct) * CH; n = L; base = NBt + NBe; shift = 8; }
  const int* idx = (stream == 0) ? dst : (stream == 1) ? src : ld;
  const int i1 = min(n, i0 + CH);
  hist[tid] = 0;
  __syncthreads();
  for (int i = i0 + tid; i < i1; i += 256) atomicAdd(&hist[idx[i] >> shift], 1);
  __syncthreads();
  int h = hist[tid];
  if (h) atomicAdd(&bcnt[base + tid], h);
}

// ---------------------------------------------------------------- tiny bucket scan (1 block)
__global__ void scan_buckets(const int* __restrict__ bcnt, int* __restrict__ boff,
                             int* __restrict__ cur, int n) {
  __shared__ int s[256];
  const int t = threadIdx.x;
  int carry = 0;
  for (int base = 0; base < n; base += 256) {
    int i = base + t;
    int v = (i < n) ? bcnt[i] : 0;
    s[t] = v;
    __syncthreads();
    for (int off = 1; off < 256; off <<= 1) {
      int x = (t >= off) ? s[t - off] : 0;
      __syncthreads();
      s[t] += x;
      __syncthreads();
    }
    if (i < n) { boff[i] = s[t] - v + carry; cur[i] = s[t] - v + carry; }
    __syncthreads();
    carry += s[255];
    __syncthreads();
  }
  if (t == 0) boff[n] = carry;
}

// ---------------------------------------------------------------- pass 1: radix bucket scatter
__global__ __launch_bounds__(256) void bucket_scatter(
    const int* __restrict__ src, const int* __restrict__ dst,
    const int* __restrict__ ls, const int* __restrict__ ld,
    int* __restrict__ cur, u64_t* __restrict__ recs,
    int E, int L, int nct, int NBt, int NBe) {
  __shared__ int hist[256];
  __shared__ int start[256];
  const int b = blockIdx.x;
  const int tid = threadIdx.x;
  int stream, i0, n, base;
  if (b < nct) { stream = 0; i0 = b * CH; n = E; base = 0; }
  else if (b < 2 * nct) { stream = 1; i0 = (b - nct) * CH; n = E; base = NBt; }
  else { stream = 2; i0 = (b - 2 * nct) * CH; n = L; base = NBt + NBe; }
  const int i1 = min(n, i0 + CH);

  hist[tid] = 0;
  __syncthreads();
  for (int i = i0 + tid; i < i1; i += 256) {
    int d = (stream == 0) ? dst[i] : (stream == 1) ? src[i] : ld[i];
    int bkt = (stream == 1) ? (d >> 9) : (d >> 8);
    atomicAdd(&hist[bkt], 1);
  }
  __syncthreads();
  int h = hist[tid];
  if (h) start[tid] = atomicAdd(&cur[base + tid], h);
  __syncthreads();
  for (int i = i0 + tid; i < i1; i += 256) {
    u64_t rec;
    int bkt;
    if (stream == 0) {
      int d = dst[i];
      rec = ((u64_t)d << 32) | (uint_t)src[i];
      bkt = d >> 8;
    } else if (stream == 1) {
      int d = src[i];
      rec = ((u64_t)d << 32) | (uint_t)dst[i];
      bkt = d >> 9;
    } else {
      int d = ld[i];
      rec = ((u64_t)d << 40) | ((u64_t)(uint_t)ls[i] << 20) | (uint_t)i;  // d:24|ls:20|i:20
      bkt = d >> 8;
    }
    int pos = start[bkt] + atomicSub(&hist[bkt], 1) - 1;
    recs[pos] = rec;
  }
}

// ---------------------------------------------------------------- pass 2: in-bucket place
// derives per-node offsets (LDS hist + block scan), writes off segments + final arrays.
__global__ __launch_bounds__(256) void place_all(
    const u64_t* __restrict__ recs, const int* __restrict__ boff,
    int* __restrict__ off_t, int* __restrict__ off_e, int* __restrict__ off_l,
    int* __restrict__ adj_t, int* __restrict__ adj_e_m, long long* __restrict__ lpair_m,
    int n_t, int n_e, int NBt, int NBe, int NBl) {
  __shared__ int sh[512];   // counts -> cursors
  __shared__ int tmp[256];
  const int b = blockIdx.x;
  const int tid = threadIdx.x;
  int stream, d0, d1, nmax;
  int* offg;
  if (b < NBt) { stream = 0; d0 = b << 8; d1 = min(n_t, d0 + 256); offg = off_t; nmax = n_t; }
  else if (b < NBt + NBe) { stream = 1; d0 = (b - NBt) << 9; d1 = min(n_e, d0 + 512); offg = off_e; nmax = n_e; }
  else { stream = 2; d0 = (b - NBt - NBe) << 8; d1 = min(n_t, d0 + 256); offg = off_l; nmax = n_t; }
  const int nn = d1 - d0;
  const int rs = boff[b], re = boff[b + 1];

  sh[tid] = 0;
  sh[tid + 256] = 0;
  __syncthreads();
  for (int i = rs + tid; i < re; i += 256) {
    u64_t rec = recs[i];
    int d = (stream == 2) ? (int)(rec >> 40) : (int)(rec >> 32);
    atomicAdd(&sh[d - d0], 1);
  }
  __syncthreads();
  int carry = 0;
  for (int c = 0; c < 2; ++c) {
    int idx = c * 256 + tid;
    int v = sh[idx];
    tmp[tid] = v;
    __syncthreads();
    for (int o = 1; o < 256; o <<= 1) {
      int x = (tid >= o) ? tmp[tid - o] : 0;
      __syncthreads();
      tmp[tid] += x;
      __syncthreads();
    }
    int excl = tmp[tid] - v + carry;
    if (idx < nn) {
      offg[d0 + idx] = rs + excl;
      sh[idx] = rs + excl;  // cursor
    }
    __syncthreads();
    carry += tmp[255];
    __syncthreads();
  }
  if (tid == 0) {
    bool last = (stream == 0 && b == NBt - 1) ||
                (stream == 1 && b == NBt + NBe - 1) ||
                (stream == 2 && b == NBt + NBe + NBl - 1);
    if (last) offg[nmax] = re;
  }
  __syncthreads();
  if (stream == 0) {
    for (int i = rs + tid; i < re; i += 256) {
      u64_t rec = recs[i];
      int d = (int)(rec >> 32);
      adj_t[atomicAdd(&sh[d - d0], 1)] = (int)rec;
    }
  } else if (stream == 1) {
    for (int i = rs + tid; i < re; i += 256) {
      u64_t rec = recs[i];
      int d = (int)(rec >> 32);
      adj_e_m[atomicAdd(&sh[d - d0], 1)] = (int)rec;
    }
  } else {
    for (int i = rs + tid; i < re; i += 256) {
      u64_t rec = recs[i];
      int d = (int)(rec >> 40);
      int lsv = (int)((rec >> 20) & 0xFFFFF);
      int li = (int)(rec & 0xFFFFF);
      lpair_m[atomicAdd(&sh[d - d0], 1)] = ((long long)lsv << 32) | (uint_t)li;
    }
  }
}

// ---------------------------------------------------------------- dual pull mean (unroll 8)
__global__ void pull_mean_dual(
    const ushort_t* __restrict__ featA, const int* __restrict__ offA, const int* __restrict__ adjA,
    ushort_t* __restrict__ outA, int nA,
    const ushort_t* __restrict__ featB, const int* __restrict__ offB, const int* __restrict__ adjB,
    ushort_t* __restrict__ outB, int nB) {
  int gid = blockIdx.x * blockDim.x + threadIdx.x;
  int wave = gid >> 6;
  int lane = gid & 63;
  int nw = (gridDim.x * blockDim.x) >> 6;
  for (int v = wave; v < nA + nB; v += nw) {
    const uint_t* f;
    const int* off;
    const int* adj;
    uint_t* o;
    int vv;
    if (v < nA) {
      f = (const uint_t*)featA; off = offA; adj = adjA; o = (uint_t*)outA; vv = v;
    } else {
      f = (const uint_t*)featB; off = offB; adj = adjB; o = (uint_t*)outB; vv = v - nA;
    }
    int s = off[vv], e = off[vv + 1];
    float axs[8], ays[8];
#pragma unroll
    for (int k = 0; k < 8; ++k) { axs[k] = 0.f; ays[k] = 0.f; }
    int i = s;
    for (; i + 8 <= e; i += 8) {
      uint_t u[8];
#pragma unroll
      for (int k = 0; k < 8; ++k) u[k] = f[(size_t)adj[i + k] * 64 + lane];
#pragma unroll
      for (int k = 0; k < 8; ++k) { axs[k] += bflo(u[k]); ays[k] += bfhi(u[k]); }
    }
    for (; i + 4 <= e; i += 4) {
      uint_t u[4];
#pragma unroll
      for (int k = 0; k < 4; ++k) u[k] = f[(size_t)adj[i + k] * 64 + lane];
#pragma unroll
      for (int k = 0; k < 4; ++k) { axs[k] += bflo(u[k]); ays[k] += bfhi(u[k]); }
    }
    for (; i < e; ++i) {
      uint_t u = f[(size_t)adj[i] * 64 + lane];
      axs[0] += bflo(u); ays[0] += bfhi(u);
    }
    float sx = ((axs[0] + axs[1]) + (axs[2] + axs[3])) + ((axs[4] + axs[5]) + (axs[6] + axs[7]));
    float sy = ((ays[0] + ays[1]) + (ays[2] + ays[3])) + ((ays[4] + ays[5]) + (ays[6] + ays[7]));
    float rd = 1.0f / fmaxf((float)(e - s), 1.0f);
    o[(size_t)vv * 64 + lane] = (uint_t)f2bf(sx * rd) | ((uint_t)f2bf(sy * rd) << 16);
  }
}

// ---------------------------------------------------------------- dual MFMA GEMM
template <bool RELU>
__global__ __launch_bounds__(256, 2) void gemm_mfma_dual(
    const ushort_t* __restrict__ aggA, const ushort_t* __restrict__ xdA,
    const ushort_t* __restrict__ wfA, const float* __restrict__ biasA,
    ushort_t* __restrict__ outA, int nA, int gA,
    const ushort_t* __restrict__ aggB, const ushort_t* __restrict__ xdB,
    const ushort_t* __restrict__ wfB, const float* __restrict__ biasB,
    ushort_t* __restrict__ outB, int nB) {
  __shared__ __align__(16) ushort_t sA[64 * 128];
  __shared__ __align__(16) ushort_t sX[64 * 128];
  const ushort_t *agg, *xd, *wfrag;
  const float* bias;
  ushort_t* outp;
  int n, b0, nbl;
  if ((int)blockIdx.x < gA) {
    agg = aggA; xd = xdA; wfrag = wfA; bias = biasA; outp = outA; n = nA;
    b0 = blockIdx.x; nbl = gA;
  } else {
    agg = aggB; xd = xdB; wfrag = wfB; bias = biasB; outp = outB; n = nB;
    b0 = blockIdx.x - gA; nbl = gridDim.x - gA;
  }
  const int t = threadIdx.x;
  const int lane = t & 63;
  const int wid = t >> 6;
  const int mrow = (wid >> 1) * 32;
  const int nhalf = (wid & 1) * 64;

  s16x8 B[8][4];
#pragma unroll
  for (int ks = 0; ks < 8; ++ks)
#pragma unroll
    for (int nfi = 0; nfi < 4; ++nfi)
      B[ks][nfi] = *(const s16x8*)(wfrag + (size_t)(((ks << 3) | ((nhalf >> 4) + nfi)) << 9) + (lane << 3));

  float bv[4];
#pragma unroll
  for (int nfi = 0; nfi < 4; ++nfi) bv[nfi] = bias[nhalf + nfi * 16 + (lane & 15)];

  const int lrow = lane >> 4;
  const int pbyte = (lane & 15) << 4;

  const int ntiles = (n + 63) >> 6;
  for (int tile = b0; tile < ntiles; tile += nbl) {
    const int row0 = tile << 6;
#pragma unroll
    for (int i = 0; i < 8; ++i) {
      int reg = (wid << 3) + i;
      int rr = ((reg & 15) << 2) + lrow;
      int row = row0 + rr;
      row = row < n ? row : n - 1;
      int pp = pbyte ^ ((rr & 7) << 4);
      const ushort_t* srcp = (reg < 16 ? agg : xd) + (size_t)row * H + (pp >> 1);
      ushort_t* ldst = (reg < 16 ? sA : sX) + ((reg & 15) << 9);
      gload_lds16(srcp, ldst);
    }
    __syncthreads();

    f32x4 acc[2][4];
#pragma unroll
    for (int mi = 0; mi < 2; ++mi)
#pragma unroll
      for (int nfi = 0; nfi < 4; ++nfi) {
        f32x4 c = {bv[nfi], bv[nfi], bv[nfi], bv[nfi]};
        acc[mi][nfi] = c;
      }

    const int rr0 = mrow + (lane & 15);
    const int rr1 = rr0 + 16;
    const int kx = (lane >> 4) << 4;
    const int sw = (rr0 & 7) << 4;
#pragma unroll
    for (int ks = 0; ks < 8; ++ks) {
      const ushort_t* base = (ks < 4) ? sA : sX;
      const int kb = (ks & 3) << 6;
      s16x8 a0 = *(const s16x8*)((const char*)base + rr0 * 256 + ((kb | kx) ^ sw));
      s16x8 a1 = *(const s16x8*)((const char*)base + rr1 * 256 + ((kb | kx) ^ sw));
#pragma unroll
      for (int nfi = 0; nfi < 4; ++nfi) {
        acc[0][nfi] = __builtin_amdgcn_mfma_f32_16x16x32_bf16(a0, B[ks][nfi], acc[0][nfi], 0, 0, 0);
        acc[1][nfi] = __builtin_amdgcn_mfma_f32_16x16x32_bf16(a1, B[ks][nfi], acc[1][nfi], 0, 0, 0);
      }
    }

#pragma unroll
    for (int mi = 0; mi < 2; ++mi) {
      int rbase = row0 + mrow + mi * 16 + ((lane >> 4) << 2);
#pragma unroll
      for (int r = 0; r < 4; ++r) {
        int row = rbase + r;
        if (row < n) {
#pragma unroll
          for (int nfi = 0; nfi < 4; ++nfi) {
            float v = acc[mi][nfi][r];
            if (RELU) v = fmaxf(v, 0.f);
            outp[(size_t)row * H + nhalf + nfi * 16 + (lane & 15)] = f2bf(v);
          }
        }
      }
    }
    __syncthreads();
  }
}

// ---------------------------------------------------------------- grouped edge dot
__global__ void edge_dot_grouped(const ushort_t* __restrict__ ze, const ushort_t* __restrict__ zt,
                                 const int* __restrict__ loff, const long long* __restrict__ lpair,
                                 float* __restrict__ out, int n_t) {
  int gid = blockIdx.x * blockDim.x + threadIdx.x;
  int wave = gid >> 6;
  int lane = gid & 63;
  int nw = (gridDim.x * blockDim.x) >> 6;
  const uint_t* fz = (const uint_t*)ze;
  const uint_t* ft = (const uint_t*)zt;
  for (int v = wave; v < n_t; v += nw) {
    int s = loff[v], e = loff[v + 1];
    if (s == e) continue;
    uint_t ub = ft[(size_t)v * 64 + lane];
    float blo = bflo(ub), bhi = bfhi(ub);
    int i = s;
    for (; i + 4 <= e; i += 4) {
      long long q0 = lpair[i], q1 = lpair[i + 1], q2 = lpair[i + 2], q3 = lpair[i + 3];
      uint_t u0 = fz[(size_t)(int)(q0 >> 32) * 64 + lane];
      uint_t u1 = fz[(size_t)(int)(q1 >> 32) * 64 + lane];
      uint_t u2 = fz[(size_t)(int)(q2 >> 32) * 64 + lane];
      uint_t u3 = fz[(size_t)(int)(q3 >> 32) * 64 + lane];
      float p0 = bflo(u0) * blo + bfhi(u0) * bhi;
      float p1 = bflo(u1) * blo + bfhi(u1) * bhi;
      float p2 = bflo(u2) * blo + bfhi(u2) * bhi;
      float p3 = bflo(u3) * blo + bfhi(u3) * bhi;
#pragma unroll
      for (int o = 32; o; o >>= 1) {
        p0 += __shfl_down(p0, o);
        p1 += __shfl_down(p1, o);
        p2 += __shfl_down(p2, o);
        p3 += __shfl_down(p3, o);
      }
      if (lane == 0) {
        __builtin_nontemporal_store(p0, &out[(int)q0]);
        __builtin_nontemporal_store(p1, &out[(int)q1]);
        __builtin_nontemporal_store(p2, &out[(int)q2]);
        __builtin_nontemporal_store(p3, &out[(int)q3]);
      }
    }
    for (; i < e; ++i) {
      long long q0 = lpair[i];
      uint_t u0 = fz[(size_t)(int)(q0 >> 32) * 64 + lane];
      float p0 = bflo(u0) * blo + bfhi(u0) * bhi;
#pragma unroll
      for (int o = 32; o; o >>= 1) p0 += __shfl_down(p0, o);
      if (lane == 0) __builtin_nontemporal_store(p0, &out[(int)q0]);
    }
  }
}

// ---------------------------------------------------------------- launch
extern "C" void kernel_launch(void* const* d_in, const int* in_sizes, int n_in,
                              void* d_out, int out_size, void* d_ws, size_t ws_size,
                              hipStream_t stream) {
  const float* x_e = (const float*)d_in[0];
  const float* x_t = (const float*)d_in[1];
  const int* src = (const int*)d_in[2];
  const int* dst = (const int*)d_in[3];
  const int* ls = (const int*)d_in[4];
  const int* ld = (const int*)d_in[5];
  const float* W1et_l = (const float*)d_in[6];
  const float* W1et_r = (const float*)d_in[7];
  const float* W1te_l = (const float*)d_in[8];
  const float* W1te_r = (const float*)d_in[9];
  const float* W2et_l = (const float*)d_in[10];
  const float* W2et_r = (const float*)d_in[11];
  const float* W2te_l = (const float*)d_in[12];
  const float* W2te_r = (const float*)d_in[13];
  const float* b1et = (const float*)d_in[14];
  const float* b1te = (const float*)d_in[15];
  const float* b2et = (const float*)d_in[16];
  const float* b2te = (const float*)d_in[17];

  const int n_e = in_sizes[0] / H;
  const int n_t = in_sizes[1] / H;
  const int E = in_sizes[2];
  const int L = in_sizes[4];
  float* out = (float*)d_out;

  const size_t fe = (size_t)n_e * H;
  const size_t ft = (size_t)n_t * H;
  ushort_t* us = (ushort_t*)d_ws;
  ushort_t* xb_e = us;               // fe
  ushort_t* xb_t = xb_e + fe;        // ft  (contiguous with xb_e for cvt)
  ushort_t* agg_e = xb_t + ft;       // fe  (layer2: z_expert in place)
  ushort_t* agg_t = agg_e + fe;      // ft  (… z_team in place)
  ushort_t* h_e = agg_t + ft;        // fe
  ushort_t* h_t = h_e + fe;          // ft
  ushort_t* wfrag = h_t + ft;        // 4*32768
  int* ib = (int*)(wfrag + 4 * 32768);

  const int Mt = n_t + 1, Me = n_e + 1, Ml = n_t + 1;
  const int NBt = (n_t + 255) >> 8;
  const int NBe = (n_e + 511) >> 9;
  const int NBl = NBt;
  const int NBtot = NBt + NBe + NBl;

  int* off = ib;                   // Mt+Me+Ml  ([off_t | off_e(+E) | off_l(+2E)])
  int* bcnt = off + Mt + Me + Ml;  // NBtot+1
  int* boff = bcnt + NBtot + 1;    // NBtot+1
  int* cur = boff + NBtot + 1;     // NBtot
  int* adj_t = cur + NBtot;        // E
  int* adj_e = adj_t + E;          // E
  long long* lpair = (long long*)(((unsigned long long)(adj_e + E) + 7) & ~7ULL);  // L
  u64_t* recs = (u64_t*)(lpair + L);  // 2E+L

  int* off_t = off;
  int* off_e = off + Mt;            // values in [E, 2E]
  int* off_l = off + Mt + Me;       // values in [2E, 2E+L]
  int* adj_e_m = adj_e - E;
  long long* lpair_m = lpair - 2 * (size_t)E;

  const int nct = (E + CH - 1) / CH;
  const int ncl = (L + CH - 1) / CH;

  const dim3 blk(256);

  // ---- prologue: cvt + wfrag + bcnt zero (merged)
  prep_kernel<<<2561, blk, 0, stream>>>(x_e, x_t, fe / 4, (fe + ft) / 4, (uint2*)xb_e,
                                        W1et_l, W1et_r, W1te_l, W1te_r,
                                        W2et_l, W2et_r, W2te_l, W2te_r,
                                        wfrag, bcnt, NBtot + 1);

  // ---- CSR build: bucket counts -> tiny scan -> radix scatter -> in-bucket place
  bucket_count<<<2 * nct + ncl, blk, 0, stream>>>(src, dst, ld, bcnt, E, L, nct, NBt, NBe);
  scan_buckets<<<1, blk, 0, stream>>>(bcnt, boff, cur, NBtot);
  bucket_scatter<<<2 * nct + ncl, blk, 0, stream>>>(src, dst, ls, ld, cur, recs,
                                                    E, L, nct, NBt, NBe);
  place_all<<<NBtot, blk, 0, stream>>>(recs, boff, off_t, off_e, off_l,
                                       adj_t, adj_e_m, lpair_m, n_t, n_e, NBt, NBe, NBl);

  const int gt = (n_t + 63) / 64, ge = (n_e + 63) / 64;
  const int gA = min(gt, 512), gB = min(ge, 512);
  const int npull = ((n_t + n_e) + 3) / 4;

  // ---- layer 1
  pull_mean_dual<<<npull, blk, 0, stream>>>(xb_e, off_t, adj_t, agg_t, n_t,
                                            xb_t, off_e, adj_e_m, agg_e, n_e);
  gemm_mfma_dual<true><<<gA + gB, blk, 0, stream>>>(
      agg_t, xb_t, wfrag + 0 * 32768, b1et, h_t, n_t, gA,
      agg_e, xb_e, wfrag + 1 * 32768, b1te, h_e, n_e);

  // ---- layer 2 (z written in place over agg)
  pull_mean_dual<<<npull, blk, 0, stream>>>(h_e, off_t, adj_t, agg_t, n_t,
                                            h_t, off_e, adj_e_m, agg_e, n_e);
  gemm_mfma_dual<false><<<gA + gB, blk, 0, stream>>>(
      agg_t, h_t, wfrag + 2 * 32768, b2et, agg_t, n_t, gA,
      agg_e, h_e, wfrag + 3 * 32768, b2te, agg_e, n_e);

  // ---- grouped edge dot readout
  edge_dot_grouped<<<(n_t + 3) / 4, blk, 0, stream>>>(agg_e, agg_t, off_l, lpair_m, out, n_t);
}